// Round 20
// baseline (579.903 us; speedup 1.0000x reference)
//
#include <hip/hip_runtime.h>

#define HID 10
#define TT  2048
#define BB  4096

typedef float f2 __attribute__((ext_vector_type(2)));

static __device__ __forceinline__ f2 pkmul(f2 a, f2 b) {
    f2 d; asm("v_pk_mul_f32 %0, %1, %2" : "=v"(d) : "v"(a), "v"(b)); return d;
}
static __device__ __forceinline__ f2 pkfma(f2 a, f2 b, f2 c) {
    f2 d; asm("v_pk_fma_f32 %0, %1, %2, %3" : "=v"(d) : "v"(a), "v"(b), "v"(c)); return d;
}

__device__ __forceinline__ float fast_tanh(float x) {
    // tanh(x) = 1 - 2/(exp2(x*2*log2e) + 1); saturates correctly at +-inf
    float e = exp2f(x * 2.885390081777926814f);
    float r = __builtin_amdgcn_rcpf(e + 1.0f);
    return fmaf(-2.0f, r, 1.0f);
}

// pack two f32 (rows A,B) into one dword of 2 bf16 (HW round)
__device__ __forceinline__ unsigned cvtpk(float a, float b) {
    unsigned r;
    asm("v_cvt_pk_bf16_f32 %0, %1, %2" : "=v"(r) : "v"(a), "v"(b));
    return r;
}
// unpack: .x = rowA (lo half), .y = rowB (hi half)
__device__ __forceinline__ f2 unbf(unsigned d) {
    f2 r;
    r.x = __uint_as_float(d << 16);
    r.y = __uint_as_float(d & 0xffff0000u);
    return r;
}

// 10-term per-unit pk dot over f2{rowA,rowB} state; two chains
#define PKDOT10(A0, A1, W, H)            \
    A0 = pkmul(W[0], H[0]);              \
    A1 = pkmul(W[1], H[1]);              \
    A0 = pkfma(W[2], H[2], A0);          \
    A1 = pkfma(W[3], H[3], A1);          \
    A0 = pkfma(W[4], H[4], A0);          \
    A1 = pkfma(W[5], H[5], A1);          \
    A0 = pkfma(W[6], H[6], A0);          \
    A1 = pkfma(W[7], H[7], A1);          \
    A0 = pkfma(W[8], H[8], A0);          \
    A1 = pkfma(W[9], H[9], A1);

// R18 structure, f2-packed: each 16-lane group serves TWO rows (lane j =
// unit j, f2 = {rowA,rowB}); every pk op advances both rows. 512 blocks x
// 2 waves = 1024 waves = 1 wave/SIMD serving the SAME total work with half
// the chain instances chip-wide (R18: 2 waves/SIMD, chains convoyed ~360
// cyc/step; here step ~ one chain ~200 cyc). Broadcast packs 2 rows into
// one dword via v_cvt_pk_bf16_f32: write b32 + read b128+b128+b64.
//   wave A: h0 recurrence + u(i-1) publish (f2 into 16-slot ring);
//           lane10 publishes {bout,bout}.
//   wave B: h1 recurrence lag-9; rider lane10 (Wout) captures out(j-1)
//           for both rows; 2-value lag-carry quad stores per row.
__global__ void __launch_bounds__(128) rnn_kernel(
    const float* __restrict__ x,    const float* __restrict__ hs,
    const float* __restrict__ Wih0, const float* __restrict__ Whh0,
    const float* __restrict__ bih0, const float* __restrict__ bhh0,
    const float* __restrict__ Wih1, const float* __restrict__ Whh1,
    const float* __restrict__ bih1, const float* __restrict__ bhh1,
    const float* __restrict__ Wout, const float* __restrict__ boutp,
    float* __restrict__ out)
{
    const int tid  = threadIdx.x;
    const bool isA = tid < 64;
    const int lane = tid & 15;           // hidden unit slot
    const int grp  = (tid >> 4) & 3;     // row-pair within block
    const int rowA = blockIdx.x * 8 + 2 * grp;
    const int rowB = rowA + 1;
    const bool act = (lane < HID);
    const bool ol  = (lane == HID);      // rider lane

    // per group 552 floats (552 mod 32 = 8); permuted bases -> phases
    // {0,16,8,24} so each 32-lane half-wave's two groups are bank-disjoint.
    //   u-ring [16 slots][16 lanes] f2 @0 (512 floats)
    //   h0 bf16x2 buf @512 (16 dwords) | h1 bf16x2 buf @528
    __shared__ float lds[4 * 552];
    const int pg = ((grp << 1) | (grp >> 1)) & 3;   // {0,2,1,3}
    float* base = &lds[pg * 552];
    f2* up = (f2*)(base) + lane;                     // u-ring, slot stride 16 f2
    unsigned* h0d = (unsigned*)(base + 512);
    unsigned* h1d = (unsigned*)(base + 528);

    const float* xrA = x   + (size_t)rowA * TT;
    const float* xrB = x   + (size_t)rowB * TT;
    float*       orA = out + (size_t)rowA * TT;
    float*       orB = out + (size_t)rowB * TT;

    // ---- role state (weights duplicated into both f2 halves) ----
    f2 W0[10], W1[10], W2[10], H0[10], H1[10];
    float wih0i = 0.f, b0c = 0.f, ub = 0.f, obias = 0.f;
    float hAf = 0.f, hBf = 0.f;
    float4 xaA, xbA, xaB, xbB;
    f2 P1 = f2{0.f, 0.f}, P2 = f2{0.f, 0.f};

    if (isA) {
        #pragma unroll
        for (int u = 0; u < 10; ++u) {
            const float w0 = act ? Whh0[lane*HID + u] : 0.f;
            const float w1 = act ? Wih1[lane*HID + u] : 0.f;
            W0[u] = f2{w0, w0};
            W1[u] = f2{w1, w1};
            H0[u] = f2{hs[rowA*HID + u], hs[rowB*HID + u]};
        }
        wih0i = act ? Wih0[lane] : 0.f;
        b0c   = act ? (bih0[lane] + bhh0[lane]) : 0.f;
        ub    = act ? (bih1[lane] + bhh1[lane]) : (ol ? boutp[0] : 0.f);
        xaA = *(const float4*)(xrA); xbA = *(const float4*)(xrA + 4);
        xaB = *(const float4*)(xrB); xbB = *(const float4*)(xrB + 4);
    } else {
        #pragma unroll
        for (int u = 0; u < 10; ++u) {
            const float w2 = act ? Whh1[lane*HID + u] : (ol ? Wout[u] : 0.f);
            W2[u] = f2{w2, w2};
            H1[u] = f2{hs[BB*HID + rowA*HID + u], hs[BB*HID + rowB*HID + u]};
        }
        obias = ol ? boutp[0] : 0.f;
    }

    // main loop: A epochs 0..255 (steps 8m..8m+7, publishes u(8m-1..8m+6));
    //            B epochs 1..256 (j = 8m-9..8m-2).
    for (int m = 0; m <= 256; ++m) {
        if (isA) {
            if (m <= 255) {
                const int mn = (m + 1 <= 255) ? m + 1 : 255;
                const float4 nA0 = *(const float4*)(xrA + 8 * mn);
                const float4 nA1 = *(const float4*)(xrA + 8 * mn + 4);
                const float4 nB0 = *(const float4*)(xrB + 8 * mn);
                const float4 nB1 = *(const float4*)(xrB + 8 * mn + 4);
                const float xsA[8] = {xaA.x, xaA.y, xaA.z, xaA.w,
                                      xbA.x, xbA.y, xbA.z, xbA.w};
                const float xsB[8] = {xaB.x, xaB.y, xaB.z, xaB.w,
                                      xbB.x, xbB.y, xbB.z, xbB.w};
                const int sb = (m & 1) * 8;
                #pragma unroll
                for (int k = 0; k < 8; ++k) {
                    // h0(i) = tanh(x(i)*wih0 + Whh0 . h0(i-1) + b0), 2 rows
                    f2 a0, a1; PKDOT10(a0, a1, W0, H0);
                    const float sA = (fmaf(xsA[k], wih0i, b0c) + a0.x) + a1.x;
                    const float sB = (fmaf(xsB[k], wih0i, b0c) + a0.y) + a1.y;
                    const float hA = fast_tanh(sA);
                    const float hB = fast_tanh(sB);
                    hAf = hA; hBf = hB;
                    h0d[lane] = cvtpk(hA, hB);
                    __builtin_amdgcn_wave_barrier();
                    const uint4 rb = *(const uint4*)(h0d);      // units 0-3
                    const uint4 rc = *(const uint4*)(h0d + 4);  // units 4-7
                    const uint2 rd = *(const uint2*)(h0d + 8);  // units 8-9
                    // u(i-1) on OLD H0 (covers readback latency)
                    f2 u0, u1; PKDOT10(u0, u1, W1, H0);
                    f2 uo;
                    uo.x = (ub + u0.x) + u1.x;
                    uo.y = (ub + u0.y) + u1.y;
                    up[((sb + k + 15) & 15) * 16] = uo;
                    H0[0] = unbf(rb.x); H0[1] = unbf(rb.y);
                    H0[2] = unbf(rb.z); H0[3] = unbf(rb.w);
                    H0[4] = unbf(rc.x); H0[5] = unbf(rc.y);
                    H0[6] = unbf(rc.z); H0[7] = unbf(rc.w);
                    H0[8] = unbf(rd.x); H0[9] = unbf(rd.y);
                }
                xaA = nA0; xbA = nA1; xaB = nB0; xbB = nB1;
            }
        } else {
            if (m >= 1) {
                const int bb = (m & 1) ? 15 : 7;
                f2 u[8];
                #pragma unroll
                for (int k = 0; k < 8; ++k)
                    u[k] = up[((bb + k) & 15) * 16];
                f2 c[8];
                #pragma unroll
                for (int k = 0; k < 8; ++k) {
                    // j = 8m-9+k; h1(j) = tanh(u(j) + Whh1 . h1(j-1)), 2 rows
                    f2 a0, a1; PKDOT10(a0, a1, W2, H1);
                    f2 s1;
                    s1.x = (u[k].x + a0.x) + a1.x;   // lane10: out(j-1) rowA
                    s1.y = (u[k].y + a0.y) + a1.y;   // lane10: out(j-1) rowB
                    c[k] = s1;
                    const float hA = fast_tanh(s1.x);
                    const float hB = fast_tanh(s1.y);
                    h1d[lane] = cvtpk(hA, hB);
                    __builtin_amdgcn_wave_barrier();
                    const uint4 qb = *(const uint4*)(h1d);
                    const uint4 qc = *(const uint4*)(h1d + 4);
                    const uint2 qd = *(const uint2*)(h1d + 8);
                    if (k > 0 || m > 1) {            // mask j = -1 (m=1,k=0)
                        H1[0] = unbf(qb.x); H1[1] = unbf(qb.y);
                        H1[2] = unbf(qb.z); H1[3] = unbf(qb.w);
                        H1[4] = unbf(qc.x); H1[5] = unbf(qc.y);
                        H1[6] = unbf(qc.z); H1[7] = unbf(qc.w);
                        H1[8] = unbf(qd.x); H1[9] = unbf(qd.y);
                    }
                }
                // c[k] = out(8m-10+k); quads with 2-value carry, per row
                if (ol) {
                    if (m == 1) {
                        *(float4*)(orA) = make_float4(c[2].x, c[3].x, c[4].x, c[5].x);
                        *(float4*)(orB) = make_float4(c[2].y, c[3].y, c[4].y, c[5].y);
                    } else {
                        *(float4*)(orA + 8*m - 12) = make_float4(P1.x, P2.x, c[0].x, c[1].x);
                        *(float4*)(orA + 8*m - 8)  = make_float4(c[2].x, c[3].x, c[4].x, c[5].x);
                        *(float4*)(orB + 8*m - 12) = make_float4(P1.y, P2.y, c[0].y, c[1].y);
                        *(float4*)(orB + 8*m - 8)  = make_float4(c[2].y, c[3].y, c[4].y, c[5].y);
                    }
                }
                P1 = c[6]; P2 = c[7];
            }
        }
        __syncthreads();
    }

    // ---- tail: u(2047) publish by A, then B computes h1(2047) + outs ----
    if (isA) {
        f2 u0, u1; PKDOT10(u0, u1, W1, H0);          // H0 = h0(2047)
        f2 uo;
        uo.x = (ub + u0.x) + u1.x;
        uo.y = (ub + u0.y) + u1.y;
        up[15 * 16] = uo;                            // slot 2047 & 15
    }
    __syncthreads();
    if (!isA) {
        const f2 u47 = up[15 * 16];
        f2 a0, a1; PKDOT10(a0, a1, W2, H1);          // H1 = h1(2046)
        f2 s46;
        s46.x = (u47.x + a0.x) + a1.x;               // lane10: out(2046)
        s46.y = (u47.y + a0.y) + a1.y;
        const float hA = fast_tanh(s46.x);
        const float hB = fast_tanh(s46.y);
        h1d[lane] = cvtpk(hA, hB);
        __builtin_amdgcn_wave_barrier();
        const uint4 qb = *(const uint4*)(h1d);
        const uint4 qc = *(const uint4*)(h1d + 4);
        const uint2 qd = *(const uint2*)(h1d + 8);
        H1[0] = unbf(qb.x); H1[1] = unbf(qb.y);
        H1[2] = unbf(qb.z); H1[3] = unbf(qb.w);
        H1[4] = unbf(qc.x); H1[5] = unbf(qc.y);
        H1[6] = unbf(qc.z); H1[7] = unbf(qc.w);
        H1[8] = unbf(qd.x); H1[9] = unbf(qd.y);      // h1(2047)
        f2 b0_, b1_; PKDOT10(b0_, b1_, W2, H1);
        f2 o47;
        o47.x = (obias + b0_.x) + b1_.x;             // lane10: out(2047)
        o47.y = (obias + b0_.y) + b1_.y;
        if (ol) {
            *(float4*)(orA + TT - 4) = make_float4(P1.x, P2.x, s46.x, o47.x);
            *(float4*)(orB + TT - 4) = make_float4(P1.y, P2.y, s46.y, o47.y);
        }
        if (act) {
            out[(size_t)BB*TT + (size_t)BB*HID + (size_t)rowA*HID + lane] = hA;
            out[(size_t)BB*TT + (size_t)BB*HID + (size_t)rowB*HID + lane] = hB;
        }
    } else {
        if (act) {
            out[(size_t)BB*TT + (size_t)rowA*HID + lane] = hAf;   // h0(2047)
            out[(size_t)BB*TT + (size_t)rowB*HID + lane] = hBf;
        }
    }
}

extern "C" void kernel_launch(void* const* d_in, const int* in_sizes, int n_in,
                              void* d_out, int out_size, void* d_ws, size_t ws_size,
                              hipStream_t stream) {
    const float* x    = (const float*)d_in[0];
    const float* hs   = (const float*)d_in[1];
    const float* Wih0 = (const float*)d_in[2];
    const float* Whh0 = (const float*)d_in[3];
    const float* bih0 = (const float*)d_in[4];
    const float* bhh0 = (const float*)d_in[5];
    const float* Wih1 = (const float*)d_in[6];
    const float* Whh1 = (const float*)d_in[7];
    const float* bih1 = (const float*)d_in[8];
    const float* bhh1 = (const float*)d_in[9];
    const float* Wout = (const float*)d_in[10];
    const float* bout = (const float*)d_in[11];
    float* out = (float*)d_out;

    dim3 grid(BB / 8), block(128);
    hipLaunchKernelGGL(rnn_kernel, grid, block, 0, stream,
        x, hs, Wih0, Whh0, bih0, bhh0, Wih1, Whh1, bih1, bhh1, Wout, bout, out);
}

// Round 21
// 310.608 us; speedup vs baseline: 1.8670x; 1.8670x over previous
//
#include <hip/hip_runtime.h>

#define HID 10
#define TT  2048
#define BB  4096

typedef float f2 __attribute__((ext_vector_type(2)));

static __device__ __forceinline__ f2 pkmul(f2 a, f2 b) {
    f2 d; asm("v_pk_mul_f32 %0, %1, %2" : "=v"(d) : "v"(a), "v"(b)); return d;
}
static __device__ __forceinline__ f2 pkfma(f2 a, f2 b, f2 c) {
    f2 d; asm("v_pk_fma_f32 %0, %1, %2, %3" : "=v"(d) : "v"(a), "v"(b), "v"(c)); return d;
}

__device__ __forceinline__ float fast_tanh(float x) {
    // tanh(x) = 1 - 2/(exp2(x*2*log2e) + 1); saturates correctly at +-inf
    float e = exp2f(x * 2.885390081777926814f);
    float r = __builtin_amdgcn_rcpf(e + 1.0f);
    return fmaf(-2.0f, r, 1.0f);
}

#define PKDOT(ACC, W, H)                 \
    ACC = pkmul(W[0], H[0]);             \
    ACC = pkfma(W[1], H[1], ACC);        \
    ACC = pkfma(W[2], H[2], ACC);        \
    ACC = pkfma(W[3], H[3], ACC);        \
    ACC = pkfma(W[4], H[4], ACC);

// R18 (277us best) + two surgical fixes:
//  (1) B-chain cover: the out-dot (Wout . h1(j-1) + bout) is detached from
//      the lane-10 rider into a uniform pk-dot on the OLD H1, placed in the
//      h1-readback latency window (mirrors A's u-dot trick). B's exposed
//      readback shrinks by ~28 cyc; B was the binding pole (176 cyc x 2-wave
//      convoy ~ 324 cyc/step measured).
//  (2) half-wave bank-phase permute {0,16,8,24} (R19-proven) removes R18's
//      8 counted conflict-cycles/block-step (1.678e7 total).
//   wave A: h0 recurrence; u(i-1) on OLD H0 (readback cover) published as
//           one f32/lane into a 16-slot ring. Lane10 publishes b_out (dead).
//   wave B: h1 recurrence lag-9; out(j-1) via the detached Wo-dot; 2-value
//           lag-carry quad stores. Barrier once per 8-step epoch.
__global__ void __launch_bounds__(128) rnn_kernel(
    const float* __restrict__ x,    const float* __restrict__ hs,
    const float* __restrict__ Wih0, const float* __restrict__ Whh0,
    const float* __restrict__ bih0, const float* __restrict__ bhh0,
    const float* __restrict__ Wih1, const float* __restrict__ Whh1,
    const float* __restrict__ bih1, const float* __restrict__ bhh1,
    const float* __restrict__ Wout, const float* __restrict__ boutp,
    float* __restrict__ out)
{
    const int tid  = threadIdx.x;
    const bool isA = tid < 64;
    const int lane = tid & 15;           // hidden unit slot
    const int grp  = (tid >> 4) & 3;     // row within block
    const int row  = blockIdx.x * 4 + grp;
    const bool act = (lane < HID);
    const bool ol  = (lane == HID);      // store lane

    // stride 296 (mod 32 = 8); permuted bases {0,2,1,3} give half-wave
    // phases {0,16} / {8,24} -> each 32-lane half's two groups bank-disjoint.
    // Regions per group: u-ring [16][16] f32 @0, h0 buf @256, h1 buf @280.
    __shared__ float lds[4 * 296];
    const int pg = ((grp << 1) | (grp >> 1)) & 3;   // {0,2,1,3}
    float* base = &lds[pg * 296];
    float* up   = base + lane;           // u-ring lane pointer
    float* h0b  = base + 256;
    float* h1b  = base + 280;

    const float* xrow = x   + (size_t)row * TT;
    float*       orow = out + (size_t)row * TT;

    // ---- role state ----
    f2 W0[5], W1[5], W2[5], Wo[5], H0[5], H1[5];
    float wih0i = 0.f, b0c = 0.f, ub = 0.f, obias = 0.f;
    float hown = 0.f;
    float4 xa = make_float4(0,0,0,0), xb = make_float4(0,0,0,0);
    float P1 = 0.f, P2 = 0.f;

    if (isA) {
        #pragma unroll
        for (int j = 0; j < 5; ++j) {
            W0[j] = act ? f2{Whh0[lane*HID + 2*j], Whh0[lane*HID + 2*j+1]}
                        : f2{0.f, 0.f};
            W1[j] = act ? f2{Wih1[lane*HID + 2*j], Wih1[lane*HID + 2*j+1]}
                        : f2{0.f, 0.f};
            H0[j] = f2{hs[row*HID + 2*j], hs[row*HID + 2*j+1]};
        }
        wih0i = act ? Wih0[lane] : 0.f;
        b0c   = act ? (bih0[lane] + bhh0[lane]) : 0.f;
        ub    = act ? (bih1[lane] + bhh1[lane]) : (ol ? boutp[0] : 0.f);
        hown  = act ? hs[row*HID + lane] : 0.f;
        xa = *(const float4*)(xrow);
        xb = *(const float4*)(xrow + 4);
    } else {
        #pragma unroll
        for (int j = 0; j < 5; ++j) {
            W2[j] = act ? f2{Whh1[lane*HID + 2*j], Whh1[lane*HID + 2*j+1]}
                        : f2{0.f, 0.f};
            Wo[j] = f2{Wout[2*j], Wout[2*j+1]};      // uniform on all lanes
            H1[j] = f2{hs[BB*HID + row*HID + 2*j], hs[BB*HID + row*HID + 2*j+1]};
        }
        obias = boutp[0];                             // uniform on all lanes
    }

    // main loop: A epochs 0..255 (steps 8m..8m+7, publishes u(8m-1..8m+6));
    //            B epochs 1..256 (j = 8m-9..8m-2, all u's already published).
    for (int m = 0; m <= 256; ++m) {
        if (isA) {
            if (m <= 255) {
                const int mn = (m + 1 <= 255) ? m + 1 : 255;
                const float4 xn0 = *(const float4*)(xrow + 8 * mn);
                const float4 xn1 = *(const float4*)(xrow + 8 * mn + 4);
                const float xs[8] = {xa.x, xa.y, xa.z, xa.w,
                                     xb.x, xb.y, xb.z, xb.w};
                const int sb = (m & 1) * 8;
                #pragma unroll
                for (int k = 0; k < 8; ++k) {
                    // h0(i) = tanh(x(i)*wih0 + Whh0 . h0(i-1) + b0)
                    f2 ac; PKDOT(ac, W0, H0);
                    const float s0 = fmaf(xs[k], wih0i, b0c);
                    hown = fast_tanh((s0 + ac.x) + ac.y);
                    h0b[lane] = hown;
                    __builtin_amdgcn_wave_barrier();
                    const float4 r0 = *(const float4*)(h0b);      // issued early
                    const float4 r1 = *(const float4*)(h0b + 4);
                    const f2     r2 = *(const f2*)(h0b + 8);
                    // u(i-1) on OLD H0 (covers readback latency)
                    f2 uc; PKDOT(uc, W1, H0);
                    up[((sb + k + 15) & 15) * 16] = (ub + uc.x) + uc.y;
                    H0[0] = f2{r0.x, r0.y}; H0[1] = f2{r0.z, r0.w};
                    H0[2] = f2{r1.x, r1.y}; H0[3] = f2{r1.z, r1.w};
                    H0[4] = r2;
                }
                xa = xn0; xb = xn1;
            }
        } else {
            if (m >= 1) {
                const int bb = (m & 1) ? 15 : 7;   // first slot of this epoch
                float u[8];
                #pragma unroll
                for (int k = 0; k < 8; ++k)
                    u[k] = up[((bb + k) & 15) * 16];
                float c[8];
                #pragma unroll
                for (int k = 0; k < 8; ++k) {
                    // j = 8m-9+k; h1(j) = tanh(u(j) + Whh1 . h1(j-1))
                    f2 ac; PKDOT(ac, W2, H1);
                    const float s1 = (u[k] + ac.x) + ac.y;
                    const float hn = fast_tanh(s1);
                    h1b[lane] = hn;
                    __builtin_amdgcn_wave_barrier();
                    const float4 q0 = *(const float4*)(h1b);      // issued early
                    const float4 q1 = *(const float4*)(h1b + 4);
                    const f2     q2 = *(const f2*)(h1b + 8);
                    // out(j-1) on OLD H1 (covers readback latency)
                    f2 oc; PKDOT(oc, Wo, H1);
                    c[k] = (obias + oc.x) + oc.y;
                    if (k > 0 || m > 1) {     // mask j = -1 (m=1, k=0)
                        H1[0] = f2{q0.x, q0.y}; H1[1] = f2{q0.z, q0.w};
                        H1[2] = f2{q1.x, q1.y}; H1[3] = f2{q1.z, q1.w};
                        H1[4] = q2;
                    }
                }
                // c[k] = out(8m-10+k); quads with 2-value carry
                if (ol) {
                    if (m == 1) {
                        *(float4*)(orow) = make_float4(c[2], c[3], c[4], c[5]);
                    } else {
                        *(float4*)(orow + 8*m - 12) = make_float4(P1, P2, c[0], c[1]);
                        *(float4*)(orow + 8*m - 8)  = make_float4(c[2], c[3], c[4], c[5]);
                    }
                }
                P1 = c[6]; P2 = c[7];
            }
        }
        __syncthreads();
    }

    // ---- tail: u(2047) publish by A, then B computes h1(2047) + outs ----
    if (isA) {
        f2 uc; PKDOT(uc, W1, H0);                // H0 = h0(2047)
        up[15 * 16] = (ub + uc.x) + uc.y;        // slot 2047 & 15 = 15
    }
    __syncthreads();
    if (!isA) {
        const float u47 = up[15 * 16];
        f2 ac; PKDOT(ac, W2, H1);                // H1 = h1(2046)
        const float s = (u47 + ac.x) + ac.y;     // pre-tanh h1(2047)
        const float h1f = fast_tanh(s);
        h1b[lane] = h1f;
        __builtin_amdgcn_wave_barrier();
        const float4 q0 = *(const float4*)(h1b);
        const float4 q1 = *(const float4*)(h1b + 4);
        const f2     q2 = *(const f2*)(h1b + 8);
        f2 o0; PKDOT(o0, Wo, H1);                // out(2046) on OLD H1
        const float o46 = (obias + o0.x) + o0.y;
        H1[0] = f2{q0.x, q0.y}; H1[1] = f2{q0.z, q0.w};
        H1[2] = f2{q1.x, q1.y}; H1[3] = f2{q1.z, q1.w};
        H1[4] = q2;                              // h1(2047)
        f2 o1; PKDOT(o1, Wo, H1);
        const float o47 = (obias + o1.x) + o1.y; // out(2047)
        if (ol)
            *(float4*)(orow + TT - 4) = make_float4(P1, P2, o46, o47);
        if (act)
            out[(size_t)BB*TT + (size_t)BB*HID + (size_t)row*HID + lane] = h1f;
    } else {
        if (act)
            out[(size_t)BB*TT + (size_t)row*HID + lane] = hown;   // h0(2047)
    }
}

extern "C" void kernel_launch(void* const* d_in, const int* in_sizes, int n_in,
                              void* d_out, int out_size, void* d_ws, size_t ws_size,
                              hipStream_t stream) {
    const float* x    = (const float*)d_in[0];
    const float* hs   = (const float*)d_in[1];
    const float* Wih0 = (const float*)d_in[2];
    const float* Whh0 = (const float*)d_in[3];
    const float* bih0 = (const float*)d_in[4];
    const float* bhh0 = (const float*)d_in[5];
    const float* Wih1 = (const float*)d_in[6];
    const float* Whh1 = (const float*)d_in[7];
    const float* bih1 = (const float*)d_in[8];
    const float* bhh1 = (const float*)d_in[9];
    const float* Wout = (const float*)d_in[10];
    const float* bout = (const float*)d_in[11];
    float* out = (float*)d_out;

    dim3 grid(BB / 4), block(128);
    hipLaunchKernelGGL(rnn_kernel, grid, block, 0, stream,
        x, hs, Wih0, Whh0, bih0, bhh0, Wih1, Whh1, bih1, bhh1, Wout, bout, out);
}

// Round 22
// 263.242 us; speedup vs baseline: 2.2029x; 1.1799x over previous
//
#include <hip/hip_runtime.h>

#define HID 10
#define TT  2048
#define BB  4096

typedef float f2 __attribute__((ext_vector_type(2)));

static __device__ __forceinline__ f2 pkmul(f2 a, f2 b) {
    f2 d; asm("v_pk_mul_f32 %0, %1, %2" : "=v"(d) : "v"(a), "v"(b)); return d;
}
static __device__ __forceinline__ f2 pkfma(f2 a, f2 b, f2 c) {
    f2 d; asm("v_pk_fma_f32 %0, %1, %2, %3" : "=v"(d) : "v"(a), "v"(b), "v"(c)); return d;
}

__device__ __forceinline__ float fast_tanh(float x) {
    // tanh(x) = 1 - 2/(exp2(x*2*log2e) + 1); saturates correctly at +-inf
    float e = exp2f(x * 2.885390081777926814f);
    float r = __builtin_amdgcn_rcpf(e + 1.0f);
    return fmaf(-2.0f, r, 1.0f);
}

#define PKDOT(ACC, W, H)                 \
    ACC = pkmul(W[0], H[0]);             \
    ACC = pkfma(W[1], H[1], ACC);        \
    ACC = pkfma(W[2], H[2], ACC);        \
    ACC = pkfma(W[3], H[3], ACC);        \
    ACC = pkfma(W[4], H[4], ACC);

// R18 (277us, session best) + two zero-issue-cost tweaks:
//  (1) T5 s_setprio: chain-phase (recurrence dot -> tanh -> h write) runs at
//      prio 1, filler phase (readback consume, u-dot, publish) at prio 0.
//      A/B waves are role-diverse (T5's prerequisite): a chain-phase wave
//      wins issue arbitration against a filler-phase co-resident. R21 showed
//      per-wave windows are gone (added issue -> 1:1 dur); only cross-wave
//      arbitration can attack the ~150 cyc/step co-stall.
//  (2) half-wave bank-phase permute {0,16,8,24} (R21-proven correct+free):
//      removes the 8 counted conflict-cycles/block-step.
//   wave A: h0 recurrence; u(i-1) = Wih1.h0(i-1)+b1 on the OLD H0 (readback
//           cover), published as one f32/lane into a 16-slot ring; lane10
//           publishes b_out.
//   wave B: h1 recurrence lag-9; lane10 rides Wout on the Whh1 dot -> its
//           pre-tanh sum = out(j-1); 2-value lag-carry quad stores.
// Barrier once per 8-step epoch. 2048 waves = 2/SIMD.
__global__ void __launch_bounds__(128) rnn_kernel(
    const float* __restrict__ x,    const float* __restrict__ hs,
    const float* __restrict__ Wih0, const float* __restrict__ Whh0,
    const float* __restrict__ bih0, const float* __restrict__ bhh0,
    const float* __restrict__ Wih1, const float* __restrict__ Whh1,
    const float* __restrict__ bih1, const float* __restrict__ bhh1,
    const float* __restrict__ Wout, const float* __restrict__ boutp,
    float* __restrict__ out)
{
    const int tid  = threadIdx.x;
    const bool isA = tid < 64;
    const int lane = tid & 15;           // hidden unit slot
    const int grp  = (tid >> 4) & 3;     // row within block
    const int row  = blockIdx.x * 4 + grp;
    const bool act = (lane < HID);
    const bool ol  = (lane == HID);      // rider lane

    // stride 296 (mod 32 = 8); permuted bases {0,2,1,3} -> half-wave bank
    // phases {0,16}/{8,24}: each 32-lane half's two groups bank-disjoint.
    // Regions per group: u-ring [16][16] f32 @0, h0 buf @256, h1 buf @280.
    __shared__ float lds[4 * 296];
    const int pg = ((grp << 1) | (grp >> 1)) & 3;   // {0,2,1,3}
    float* base = &lds[pg * 296];
    float* up   = base + lane;           // u-ring lane pointer
    float* h0b  = base + 256;
    float* h1b  = base + 280;

    const float* xrow = x   + (size_t)row * TT;
    float*       orow = out + (size_t)row * TT;

    // ---- role state ----
    f2 W0[5], W1[5], W2[5], H0[5], H1[5];
    float wih0i = 0.f, b0c = 0.f, ub = 0.f, obias = 0.f;
    float hown = 0.f;
    float4 xa = make_float4(0,0,0,0), xb = make_float4(0,0,0,0);
    float P1 = 0.f, P2 = 0.f;

    if (isA) {
        #pragma unroll
        for (int j = 0; j < 5; ++j) {
            W0[j] = act ? f2{Whh0[lane*HID + 2*j], Whh0[lane*HID + 2*j+1]}
                        : f2{0.f, 0.f};
            W1[j] = act ? f2{Wih1[lane*HID + 2*j], Wih1[lane*HID + 2*j+1]}
                        : f2{0.f, 0.f};
            H0[j] = f2{hs[row*HID + 2*j], hs[row*HID + 2*j+1]};
        }
        wih0i = act ? Wih0[lane] : 0.f;
        b0c   = act ? (bih0[lane] + bhh0[lane]) : 0.f;
        ub    = act ? (bih1[lane] + bhh1[lane]) : (ol ? boutp[0] : 0.f);
        hown  = act ? hs[row*HID + lane] : 0.f;
        xa = *(const float4*)(xrow);
        xb = *(const float4*)(xrow + 4);
    } else {
        #pragma unroll
        for (int j = 0; j < 5; ++j) {
            W2[j] = act ? f2{Whh1[lane*HID + 2*j], Whh1[lane*HID + 2*j+1]}
                  : (ol ? f2{Wout[2*j], Wout[2*j+1]} : f2{0.f, 0.f});
            H1[j] = f2{hs[BB*HID + row*HID + 2*j], hs[BB*HID + row*HID + 2*j+1]};
        }
        obias = ol ? boutp[0] : 0.f;
    }

    // main loop: A epochs 0..255 (steps 8m..8m+7, publishes u(8m-1..8m+6));
    //            B epochs 1..256 (j = 8m-9..8m-2, all u's already published).
    for (int m = 0; m <= 256; ++m) {
        if (isA) {
            if (m <= 255) {
                const int mn = (m + 1 <= 255) ? m + 1 : 255;
                const float4 xn0 = *(const float4*)(xrow + 8 * mn);
                const float4 xn1 = *(const float4*)(xrow + 8 * mn + 4);
                const float xs[8] = {xa.x, xa.y, xa.z, xa.w,
                                     xb.x, xb.y, xb.z, xb.w};
                const int sb = (m & 1) * 8;
                #pragma unroll
                for (int k = 0; k < 8; ++k) {
                    // ---- chain phase: prio 1 ----
                    __builtin_amdgcn_s_setprio(1);
                    f2 ac; PKDOT(ac, W0, H0);
                    const float s0 = fmaf(xs[k], wih0i, b0c);
                    hown = fast_tanh((s0 + ac.x) + ac.y);
                    h0b[lane] = hown;
                    __builtin_amdgcn_s_setprio(0);
                    __builtin_amdgcn_wave_barrier();
                    // ---- filler phase: readback + u-dot on OLD H0 ----
                    const float4 r0 = *(const float4*)(h0b);
                    const float4 r1 = *(const float4*)(h0b + 4);
                    const f2     r2 = *(const f2*)(h0b + 8);
                    f2 uc; PKDOT(uc, W1, H0);
                    up[((sb + k + 15) & 15) * 16] = (ub + uc.x) + uc.y;
                    H0[0] = f2{r0.x, r0.y}; H0[1] = f2{r0.z, r0.w};
                    H0[2] = f2{r1.x, r1.y}; H0[3] = f2{r1.z, r1.w};
                    H0[4] = r2;
                }
                xa = xn0; xb = xn1;
            }
        } else {
            if (m >= 1) {
                const int bb = (m & 1) ? 15 : 7;   // first slot of this epoch
                float u[8];
                #pragma unroll
                for (int k = 0; k < 8; ++k)
                    u[k] = up[((bb + k) & 15) * 16];
                float c[8];
                #pragma unroll
                for (int k = 0; k < 8; ++k) {
                    // ---- chain phase: prio 1 ----
                    __builtin_amdgcn_s_setprio(1);
                    f2 ac; PKDOT(ac, W2, H1);
                    const float s1 = (u[k] + ac.x) + ac.y;  // lane10: out(j-1)
                    c[k] = s1;
                    const float hn = fast_tanh(s1);
                    h1b[lane] = hn;
                    __builtin_amdgcn_s_setprio(0);
                    __builtin_amdgcn_wave_barrier();
                    // ---- filler phase: readback consume ----
                    const float4 q0 = *(const float4*)(h1b);
                    const float4 q1 = *(const float4*)(h1b + 4);
                    const f2     q2 = *(const f2*)(h1b + 8);
                    if (k > 0 || m > 1) {     // mask j = -1 (m=1, k=0)
                        H1[0] = f2{q0.x, q0.y}; H1[1] = f2{q0.z, q0.w};
                        H1[2] = f2{q1.x, q1.y}; H1[3] = f2{q1.z, q1.w};
                        H1[4] = q2;
                    }
                }
                // c[k] = out(8m-10+k); quads with 2-value carry
                if (ol) {
                    if (m == 1) {
                        *(float4*)(orow) = make_float4(c[2], c[3], c[4], c[5]);
                    } else {
                        *(float4*)(orow + 8*m - 12) = make_float4(P1, P2, c[0], c[1]);
                        *(float4*)(orow + 8*m - 8)  = make_float4(c[2], c[3], c[4], c[5]);
                    }
                }
                P1 = c[6]; P2 = c[7];
            }
        }
        __syncthreads();
    }

    // ---- tail: u(2047) publish by A, then B computes h1(2047) + out ----
    if (isA) {
        f2 uc; PKDOT(uc, W1, H0);                // H0 = h0(2047)
        up[15 * 16] = (ub + uc.x) + uc.y;        // slot 2047 & 15 = 15
    }
    __syncthreads();
    if (!isA) {
        const float u47 = up[15 * 16];
        f2 ac; PKDOT(ac, W2, H1);                // H1 = h1(2046)
        const float sA = (u47 + ac.x) + ac.y;    // lane10: out(2046)
        const float h1f = fast_tanh(sA);
        h1b[lane] = h1f;
        __builtin_amdgcn_wave_barrier();
        const float4 q0 = *(const float4*)(h1b);
        const float4 q1 = *(const float4*)(h1b + 4);
        const f2     q2 = *(const f2*)(h1b + 8);
        H1[0] = f2{q0.x, q0.y}; H1[1] = f2{q0.z, q0.w};
        H1[2] = f2{q1.x, q1.y}; H1[3] = f2{q1.z, q1.w};
        H1[4] = q2;                              // h1(2047)
        f2 a2; PKDOT(a2, W2, H1);
        const float o47 = (obias + a2.x) + a2.y; // lane10: out(2047)
        if (ol)
            *(float4*)(orow + TT - 4) = make_float4(P1, P2, sA, o47);
        if (act)
            out[(size_t)BB*TT + (size_t)BB*HID + (size_t)row*HID + lane] = h1f;
    } else {
        if (act)
            out[(size_t)BB*TT + (size_t)row*HID + lane] = hown;   // h0(2047)
    }
}

extern "C" void kernel_launch(void* const* d_in, const int* in_sizes, int n_in,
                              void* d_out, int out_size, void* d_ws, size_t ws_size,
                              hipStream_t stream) {
    const float* x    = (const float*)d_in[0];
    const float* hs   = (const float*)d_in[1];
    const float* Wih0 = (const float*)d_in[2];
    const float* Whh0 = (const float*)d_in[3];
    const float* bih0 = (const float*)d_in[4];
    const float* bhh0 = (const float*)d_in[5];
    const float* Wih1 = (const float*)d_in[6];
    const float* Whh1 = (const float*)d_in[7];
    const float* bih1 = (const float*)d_in[8];
    const float* bhh1 = (const float*)d_in[9];
    const float* Wout = (const float*)d_in[10];
    const float* bout = (const float*)d_in[11];
    float* out = (float*)d_out;

    dim3 grid(BB / 4), block(128);
    hipLaunchKernelGGL(rnn_kernel, grid, block, 0, stream,
        x, hs, Wih0, Whh0, bih0, bhh0, Wih1, Whh1, bih1, bhh1, Wout, bout, out);
}

// Round 23
// 254.004 us; speedup vs baseline: 2.2830x; 1.0364x over previous
//
#include <hip/hip_runtime.h>

#define HID 10
#define TT  2048
#define BB  4096

typedef float f2 __attribute__((ext_vector_type(2)));

static __device__ __forceinline__ f2 pkmul(f2 a, f2 b) {
    f2 d; asm("v_pk_mul_f32 %0, %1, %2" : "=v"(d) : "v"(a), "v"(b)); return d;
}
static __device__ __forceinline__ f2 pkfma(f2 a, f2 b, f2 c) {
    f2 d; asm("v_pk_fma_f32 %0, %1, %2, %3" : "=v"(d) : "v"(a), "v"(b), "v"(c)); return d;
}

__device__ __forceinline__ float fast_tanh(float x) {
    // tanh(x) = 1 - 2/(exp2(x*2*log2e) + 1); saturates correctly at +-inf
    float e = exp2f(x * 2.885390081777926814f);
    float r = __builtin_amdgcn_rcpf(e + 1.0f);
    return fmaf(-2.0f, r, 1.0f);
}

#define PKDOT(ACC, W, H)                 \
    ACC = pkmul(W[0], H[0]);             \
    ACC = pkfma(W[1], H[1], ACC);        \
    ACC = pkfma(W[2], H[2], ACC);        \
    ACC = pkfma(W[3], H[3], ACC);        \
    ACC = pkfma(W[4], H[4], ACC);

// R22 (263us best: R18 + setprio + bank-phase permute) with 16-STEP EPOCHS:
// barriers 257 -> 129. The u-ring widens to 32 slots; A writes slots
// {16m-1..16m+14} mod 32 while B reads the complementary 16-window
// {16m-17..16m-2} -> disjoint halves, race-free. Waves realign half as
// often, cutting the per-barrier convoy (max(A,B) + pipe drain) term.
//   wave A: h0 recurrence; u(i-1) = Wih1.h0(i-1)+b1 on OLD H0 (readback
//           cover); one f32/lane publish. Lane10 publishes b_out.
//   wave B: h1 recurrence lag-17; lane10 rides Wout -> pre-tanh = out(j-1);
//           lag-carry quad stores. setprio(1) around each chain phase.
__global__ void __launch_bounds__(128) rnn_kernel(
    const float* __restrict__ x,    const float* __restrict__ hs,
    const float* __restrict__ Wih0, const float* __restrict__ Whh0,
    const float* __restrict__ bih0, const float* __restrict__ bhh0,
    const float* __restrict__ Wih1, const float* __restrict__ Whh1,
    const float* __restrict__ bih1, const float* __restrict__ bhh1,
    const float* __restrict__ Wout, const float* __restrict__ boutp,
    float* __restrict__ out)
{
    const int tid  = threadIdx.x;
    const bool isA = tid < 64;
    const int lane = tid & 15;           // hidden unit slot
    const int grp  = (tid >> 4) & 3;     // row within block
    const int row  = blockIdx.x * 4 + grp;
    const bool act = (lane < HID);
    const bool ol  = (lane == HID);      // rider lane

    // stride 552 (mod 32 = 8); permuted bases {0,2,1,3} -> half-wave bank
    // phases {0,16}/{8,24}. Regions per group: u-ring [32][16] f32 @0,
    // h0 buf @512, h1 buf @528.
    __shared__ float lds[4 * 552];
    const int pg = ((grp << 1) | (grp >> 1)) & 3;   // {0,2,1,3}
    float* base = &lds[pg * 552];
    float* up   = base + lane;           // u-ring lane pointer
    float* h0b  = base + 512;
    float* h1b  = base + 528;

    const float* xrow = x   + (size_t)row * TT;
    float*       orow = out + (size_t)row * TT;

    // ---- role state ----
    f2 W0[5], W1[5], W2[5], H0[5], H1[5];
    float wih0i = 0.f, b0c = 0.f, ub = 0.f, obias = 0.f;
    float hown = 0.f;
    float4 xa, xb, xc, xd;
    float P1 = 0.f, P2 = 0.f;

    if (isA) {
        #pragma unroll
        for (int j = 0; j < 5; ++j) {
            W0[j] = act ? f2{Whh0[lane*HID + 2*j], Whh0[lane*HID + 2*j+1]}
                        : f2{0.f, 0.f};
            W1[j] = act ? f2{Wih1[lane*HID + 2*j], Wih1[lane*HID + 2*j+1]}
                        : f2{0.f, 0.f};
            H0[j] = f2{hs[row*HID + 2*j], hs[row*HID + 2*j+1]};
        }
        wih0i = act ? Wih0[lane] : 0.f;
        b0c   = act ? (bih0[lane] + bhh0[lane]) : 0.f;
        ub    = act ? (bih1[lane] + bhh1[lane]) : (ol ? boutp[0] : 0.f);
        hown  = act ? hs[row*HID + lane] : 0.f;
        xa = *(const float4*)(xrow);
        xb = *(const float4*)(xrow + 4);
        xc = *(const float4*)(xrow + 8);
        xd = *(const float4*)(xrow + 12);
    } else {
        #pragma unroll
        for (int j = 0; j < 5; ++j) {
            W2[j] = act ? f2{Whh1[lane*HID + 2*j], Whh1[lane*HID + 2*j+1]}
                  : (ol ? f2{Wout[2*j], Wout[2*j+1]} : f2{0.f, 0.f});
            H1[j] = f2{hs[BB*HID + row*HID + 2*j], hs[BB*HID + row*HID + 2*j+1]};
        }
        obias = ol ? boutp[0] : 0.f;
    }

    // A epochs 0..127 (steps i=16m..16m+15, publishes u(16m-1..16m+14));
    // B epochs 1..128 (j = 16(m-1)-1..16(m-1)+14, lag-17 behind A's window).
    for (int m = 0; m <= 128; ++m) {
        if (isA) {
            if (m <= 127) {
                const int mn = (m + 1 <= 127) ? m + 1 : 127;
                const float4 n0 = *(const float4*)(xrow + 16 * mn);
                const float4 n1 = *(const float4*)(xrow + 16 * mn + 4);
                const float4 n2 = *(const float4*)(xrow + 16 * mn + 8);
                const float4 n3 = *(const float4*)(xrow + 16 * mn + 12);
                const float xs[16] = {xa.x, xa.y, xa.z, xa.w,
                                      xb.x, xb.y, xb.z, xb.w,
                                      xc.x, xc.y, xc.z, xc.w,
                                      xd.x, xd.y, xd.z, xd.w};
                const int sb = (m & 1) * 16;
                #pragma unroll
                for (int k = 0; k < 16; ++k) {
                    // ---- chain phase: prio 1 ----
                    __builtin_amdgcn_s_setprio(1);
                    f2 ac; PKDOT(ac, W0, H0);
                    const float s0 = fmaf(xs[k], wih0i, b0c);
                    hown = fast_tanh((s0 + ac.x) + ac.y);
                    h0b[lane] = hown;
                    __builtin_amdgcn_s_setprio(0);
                    __builtin_amdgcn_wave_barrier();
                    // ---- filler phase: readback + u-dot on OLD H0 ----
                    const float4 r0 = *(const float4*)(h0b);
                    const float4 r1 = *(const float4*)(h0b + 4);
                    const f2     r2 = *(const f2*)(h0b + 8);
                    f2 uc; PKDOT(uc, W1, H0);
                    up[((sb + k + 31) & 31) * 16] = (ub + uc.x) + uc.y;
                    H0[0] = f2{r0.x, r0.y}; H0[1] = f2{r0.z, r0.w};
                    H0[2] = f2{r1.x, r1.y}; H0[3] = f2{r1.z, r1.w};
                    H0[4] = r2;
                }
                xa = n0; xb = n1; xc = n2; xd = n3;
            }
        } else {
            if (m >= 1) {
                const int sbB = ((m - 1) & 1) * 16;
                float u[16];
                #pragma unroll
                for (int k = 0; k < 16; ++k)
                    u[k] = up[((sbB + k + 31) & 31) * 16];
                float c[16];
                #pragma unroll
                for (int k = 0; k < 16; ++k) {
                    // j = 16(m-1)-1+k; h1(j) = tanh(u(j) + Whh1 . h1(j-1))
                    __builtin_amdgcn_s_setprio(1);
                    f2 ac; PKDOT(ac, W2, H1);
                    const float s1 = (u[k] + ac.x) + ac.y;  // lane10: out(j-1)
                    c[k] = s1;
                    const float hn = fast_tanh(s1);
                    h1b[lane] = hn;
                    __builtin_amdgcn_s_setprio(0);
                    __builtin_amdgcn_wave_barrier();
                    // ---- filler phase: readback consume ----
                    const float4 q0 = *(const float4*)(h1b);
                    const float4 q1 = *(const float4*)(h1b + 4);
                    const f2     q2 = *(const f2*)(h1b + 8);
                    if (k > 0 || m > 1) {     // mask j = -1 (m=1, k=0)
                        H1[0] = f2{q0.x, q0.y}; H1[1] = f2{q0.z, q0.w};
                        H1[2] = f2{q1.x, q1.y}; H1[3] = f2{q1.z, q1.w};
                        H1[4] = q2;
                    }
                }
                // c[k] = out(16m-18+k); quads with 2-value carry
                if (ol) {
                    if (m == 1) {
                        *(float4*)(orow)     = make_float4(c[2],  c[3],  c[4],  c[5]);
                        *(float4*)(orow + 4) = make_float4(c[6],  c[7],  c[8],  c[9]);
                        *(float4*)(orow + 8) = make_float4(c[10], c[11], c[12], c[13]);
                    } else {
                        const int tb = 16 * m - 20;
                        *(float4*)(orow + tb)      = make_float4(P1,    P2,    c[0],  c[1]);
                        *(float4*)(orow + tb + 4)  = make_float4(c[2],  c[3],  c[4],  c[5]);
                        *(float4*)(orow + tb + 8)  = make_float4(c[6],  c[7],  c[8],  c[9]);
                        *(float4*)(orow + tb + 12) = make_float4(c[10], c[11], c[12], c[13]);
                    }
                }
                P1 = c[14]; P2 = c[15];
            }
        }
        __syncthreads();
    }

    // ---- tail: u(2047) publish by A, then B computes h1(2047) + out ----
    if (isA) {
        f2 uc; PKDOT(uc, W1, H0);                // H0 = h0(2047)
        up[31 * 16] = (ub + uc.x) + uc.y;        // slot 2047 & 31 = 31
    }
    __syncthreads();
    if (!isA) {
        const float u47 = up[31 * 16];
        f2 ac; PKDOT(ac, W2, H1);                // H1 = h1(2046)
        const float sA = (u47 + ac.x) + ac.y;    // lane10: out(2046)
        const float h1f = fast_tanh(sA);
        h1b[lane] = h1f;
        __builtin_amdgcn_wave_barrier();
        const float4 q0 = *(const float4*)(h1b);
        const float4 q1 = *(const float4*)(h1b + 4);
        const f2     q2 = *(const f2*)(h1b + 8);
        H1[0] = f2{q0.x, q0.y}; H1[1] = f2{q0.z, q0.w};
        H1[2] = f2{q1.x, q1.y}; H1[3] = f2{q1.z, q1.w};
        H1[4] = q2;                              // h1(2047)
        f2 a2; PKDOT(a2, W2, H1);
        const float o47 = (obias + a2.x) + a2.y; // lane10: out(2047)
        if (ol)
            *(float4*)(orow + TT - 4) = make_float4(P1, P2, sA, o47);
        if (act)
            out[(size_t)BB*TT + (size_t)BB*HID + (size_t)row*HID + lane] = h1f;
    } else {
        if (act)
            out[(size_t)BB*TT + (size_t)row*HID + lane] = hown;   // h0(2047)
    }
}

extern "C" void kernel_launch(void* const* d_in, const int* in_sizes, int n_in,
                              void* d_out, int out_size, void* d_ws, size_t ws_size,
                              hipStream_t stream) {
    const float* x    = (const float*)d_in[0];
    const float* hs   = (const float*)d_in[1];
    const float* Wih0 = (const float*)d_in[2];
    const float* Whh0 = (const float*)d_in[3];
    const float* bih0 = (const float*)d_in[4];
    const float* bhh0 = (const float*)d_in[5];
    const float* Wih1 = (const float*)d_in[6];
    const float* Whh1 = (const float*)d_in[7];
    const float* bih1 = (const float*)d_in[8];
    const float* bhh1 = (const float*)d_in[9];
    const float* Wout = (const float*)d_in[10];
    const float* bout = (const float*)d_in[11];
    float* out = (float*)d_out;

    dim3 grid(BB / 4), block(128);
    hipLaunchKernelGGL(rnn_kernel, grid, block, 0, stream,
        x, hs, Wih0, Whh0, bih0, bhh0, Wih1, Whh1, bih1, bhh1, Wout, bout, out);
}